// Round 16
// baseline (142.623 us; speedup 1.0000x reference)
//
#include <hip/hip_runtime.h>

typedef __attribute__((ext_vector_type(8))) short bf16x8;
typedef __attribute__((ext_vector_type(8))) unsigned short u16x8;
typedef __attribute__((ext_vector_type(4))) float f32x4;
typedef __attribute__((ext_vector_type(4))) unsigned int u32x4;

#define DEVI static __device__ __forceinline__

// async global->LDS, 16B per lane; gp per-lane, lp wave-uniform
typedef const __attribute__((address_space(1))) void cglobal_void;
typedef __attribute__((address_space(3))) void lds_void;
#define GLD16(gp, lp) __builtin_amdgcn_global_load_lds((cglobal_void*)(gp), (lds_void*)(lp), 16, 0, 0)

DEVI unsigned short f2bf(float x) {
  unsigned int u = __builtin_bit_cast(unsigned int, x);
  u += 0x7fffu + ((u >> 16) & 1u);   // round-to-nearest-even
  return (unsigned short)(u >> 16);
}
// hardware packed f32x2 -> bf16x2 (RNE), single VALU op
DEVI unsigned int cvtpk_bf16(float lo, float hi) {
  unsigned int r;
  asm("v_cvt_pk_bf16_f32 %0, %1, %2" : "=v"(r) : "v"(lo), "v"(hi));
  return r;
}
// raw v_exp_f32 (2^x), no libm guard sequence
DEVI float fast_exp2(float x) {
  float r;
  asm("v_exp_f32 %0, %1" : "=v"(r) : "v"(x));
  return r;
}

// ---------------- gate: sigmoid((mean|E| - 0.1)*10) per (b,l) key ----------------
__global__ void k_gate(const float* __restrict__ E, float* __restrict__ gate) {
  int i = blockIdx.x * 256 + threadIdx.x;           // 0..4095
  const float4* e = reinterpret_cast<const float4*>(E);
  float4 a = e[i * 2], b = e[i * 2 + 1];
  float s = fabsf(a.x) + fabsf(a.y) + fabsf(a.z) + fabsf(a.w)
          + fabsf(b.x) + fabsf(b.y) + fabsf(b.z) + fabsf(b.w);
  float en = s * 0.125f;
  gate[i] = 1.0f / (1.0f + __expf(-10.0f * (en - 0.1f)));
}

// ---------------- pack 4x W (1024x1024) -> transposed bf16 (z selects) ----------------
__global__ void k_pack_wT4(const float* __restrict__ W0, const float* __restrict__ W1,
                           const float* __restrict__ W2, const float* __restrict__ W3,
                           unsigned short* __restrict__ Wt) {
  const float* W = (blockIdx.z == 0) ? W0 : (blockIdx.z == 1) ? W1
                 : (blockIdx.z == 2) ? W2 : W3;
  unsigned short* D = Wt + (size_t)blockIdx.z * 1048576;
  __shared__ float tile[32][33];
  int tx = threadIdx.x & 31, ty = threadIdx.x >> 5;
  int kb = blockIdx.x * 32, nb = blockIdx.y * 32;
#pragma unroll
  for (int i = 0; i < 4; ++i)
    tile[ty + 8 * i][tx] = W[(size_t)(kb + ty + 8 * i) * 1024 + nb + tx];
  __syncthreads();
#pragma unroll
  for (int i = 0; i < 4; ++i) {
    int n = nb + ty + 8 * i;
    int k = kb + tx;
    D[(size_t)n * 1024 + k] = f2bf(tile[tx][ty + 8 * i]);
  }
}

// ---------------- bf16 GEMM main loop (O-proj): 128x128, BK=64, dbuf + global_load_lds ----------------
template <int NT>
DEVI void gemm_tile(const unsigned short* __restrict__ A,
                    const unsigned short* __restrict__ Bt,
                    unsigned short* sA0, unsigned short* sB0,
                    int m0, int n0, int tid, f32x4 acc[4][4]) {
  const int lane = tid & 63;
  const int l15 = lane & 15, l4 = lane >> 4;
  const int wave = tid >> 6;
  const int wr = wave >> 1, wc = wave & 1;
  const int wofs = (tid & 192) * 16;       // wave*1024 bytes: wave-uniform LDS base offset

  auto stage = [&](int buf, int k0) {
    unsigned short* dA = sA0 + buf * 8192;
    unsigned short* dB = sB0 + buf * 8192;
#pragma unroll
    for (int i = 0; i < 4; ++i) {
      int id = i * 256 + tid;
      int r = id >> 3, c = id & 7;
      GLD16(A + (size_t)(m0 + r) * 1024 + k0 + ((c ^ (r & 7)) << 3), (char*)dA + i * 4096 + wofs);
    }
#pragma unroll
    for (int i = 0; i < 4; ++i) {
      int id = i * 256 + tid;
      int r = id >> 3, c = id & 7;
      GLD16(Bt + (size_t)(n0 + r) * 1024 + k0 + ((c ^ (r & 7)) << 3), (char*)dB + i * 4096 + wofs);
    }
  };

  stage(0, 0);
  int cur = 0;
  for (int t = 0; t < NT; ++t) {
    __syncthreads();   // drains vmcnt for tile t; also protects buf cur^1 writes
    if (t + 1 < NT) stage(cur ^ 1, (t + 1) * 64);
    const unsigned short* cA = sA0 + cur * 8192;
    const unsigned short* cB = sB0 + cur * 8192;
#pragma unroll
    for (int kc = 0; kc < 2; ++kc) {
      bf16x8 af[4], bfr[4];
#pragma unroll
      for (int f = 0; f < 4; ++f) {
        int r = wr * 64 + f * 16 + l15;
        af[f] = *reinterpret_cast<const bf16x8*>(
            reinterpret_cast<const char*>(cA) + r * 128 + (((kc * 4 + l4) ^ (r & 7)) * 16));
      }
#pragma unroll
      for (int f = 0; f < 4; ++f) {
        int r = wc * 64 + f * 16 + l15;
        bfr[f] = *reinterpret_cast<const bf16x8*>(
            reinterpret_cast<const char*>(cB) + r * 128 + (((kc * 4 + l4) ^ (r & 7)) * 16));
      }
      __builtin_amdgcn_s_setprio(1);
#pragma unroll
      for (int fm = 0; fm < 4; ++fm)
#pragma unroll
        for (int fn = 0; fn < 4; ++fn)
          acc[fm][fn] = __builtin_amdgcn_mfma_f32_16x16x32_bf16(af[fm], bfr[fn], acc[fm][fn], 0, 0, 0);
      __builtin_amdgcn_s_setprio(0);
    }
    cur ^= 1;
  }
}

// ---------------- fused Q+K+V projection GEMM, f32-X direct (no pack pass) ----------------
// Operand-swapped: W = A (rows = d), X = B (rows = l). W staged via global_load_lds; X staged
// f32 -> regs -> cvt_pk -> swizzled ds_write (T14 split: load before compute, write after).
// Region by blockIdx.x: 0=Q (scaled 0.125*log2e), 1=K, 2=V (gated, per-head transposed).
__global__ __launch_bounds__(256) void k_gemm_qkv(const float* __restrict__ q_x,
                                                  const float* __restrict__ k_x,
                                                  const float* __restrict__ v_x,
                                                  const unsigned short* __restrict__ WhQ,
                                                  const unsigned short* __restrict__ WhK,
                                                  const unsigned short* __restrict__ WhV,
                                                  const float* __restrict__ bq,
                                                  const float* __restrict__ bk,
                                                  const float* __restrict__ bv,
                                                  const float* __restrict__ gate,
                                                  unsigned short* __restrict__ Qp,
                                                  unsigned short* __restrict__ Kp,
                                                  unsigned short* __restrict__ Vt) {
  __shared__ unsigned short sA[2][128 * 64];   // 32KB (W tiles)
  __shared__ unsigned short sB[2][128 * 64];   // 32KB (X tiles, bf16 after cvt)
  const int tid = threadIdx.x;
  const int lane = tid & 63, wave = tid >> 6;
  const int l15 = lane & 15, l4 = lane >> 4;
  const int wr = wave >> 1, wc = wave & 1;
  const int m0 = blockIdx.x * 128, n0 = blockIdx.y * 128;
  const int region = m0 >> 12;                 // 0=Q, 1=K, 2=V
  const float* X = (region == 0) ? q_x : (region == 1) ? k_x : v_x;
  const unsigned short* Wm = (region == 0) ? WhQ : (region == 1) ? WhK : WhV;
  const float* bias = (region == 0) ? bq : (region == 1) ? bk : bv;
  const int wofs = (tid & 192) * 16;
  const int xr = tid >> 1;                     // X tile row this thread stages
  const int xc = (tid & 1) * 32;               // f32 col base (32 cols per thread)
  const size_t xrow = (size_t)((m0 & 4095) + xr) * 1024;

  auto stageA = [&](int buf, int k0) {
    unsigned short* dA = &sA[buf][0];
#pragma unroll
    for (int i = 0; i < 4; ++i) {
      int id = i * 256 + tid;
      int r = id >> 3, c = id & 7;
      GLD16(Wm + (size_t)(n0 + r) * 1024 + k0 + ((c ^ (r & 7)) << 3), (char*)dA + i * 4096 + wofs);
    }
  };
  float4 xb[8];
  auto loadB = [&](int k0) {
    const float4* s4 = reinterpret_cast<const float4*>(X + xrow + k0 + xc);
#pragma unroll
    for (int i = 0; i < 8; ++i) xb[i] = s4[i];
  };
  auto writeB = [&](int buf) {
    char* base = reinterpret_cast<char*>(&sB[buf][0]) + xr * 128;
#pragma unroll
    for (int c4 = 0; c4 < 4; ++c4) {
      int c = (tid & 1) * 4 + c4;
      u32x4 wv;
      wv.x = cvtpk_bf16(xb[c4 * 2].x, xb[c4 * 2].y);
      wv.y = cvtpk_bf16(xb[c4 * 2].z, xb[c4 * 2].w);
      wv.z = cvtpk_bf16(xb[c4 * 2 + 1].x, xb[c4 * 2 + 1].y);
      wv.w = cvtpk_bf16(xb[c4 * 2 + 1].z, xb[c4 * 2 + 1].w);
      *reinterpret_cast<u32x4*>(base + ((c ^ (xr & 7)) * 16)) = wv;
    }
  };

  const f32x4 zero4 = {0.f, 0.f, 0.f, 0.f};
  f32x4 acc[4][4];
#pragma unroll
  for (int i = 0; i < 4; ++i)
#pragma unroll
    for (int j = 0; j < 4; ++j) acc[i][j] = zero4;

  // prologue: stage tile 0 (both operands)
  loadB(0);
  stageA(0, 0);
  writeB(0);
  int cur = 0;
  for (int t = 0; t < 16; ++t) {
    __syncthreads();   // drains vmcnt (W tile t, X f32 loads) + lgkm (X ds_writes)
    if (t + 1 < 16) { stageA(cur ^ 1, (t + 1) * 64); loadB((t + 1) * 64); }
    const unsigned short* cA = &sA[cur][0];
    const unsigned short* cB = &sB[cur][0];
#pragma unroll
    for (int kc = 0; kc < 2; ++kc) {
      bf16x8 af[4], bfr[4];
#pragma unroll
      for (int f = 0; f < 4; ++f) {
        int r = wr * 64 + f * 16 + l15;
        af[f] = *reinterpret_cast<const bf16x8*>(
            reinterpret_cast<const char*>(cA) + r * 128 + (((kc * 4 + l4) ^ (r & 7)) * 16));
      }
#pragma unroll
      for (int f = 0; f < 4; ++f) {
        int r = wc * 64 + f * 16 + l15;
        bfr[f] = *reinterpret_cast<const bf16x8*>(
            reinterpret_cast<const char*>(cB) + r * 128 + (((kc * 4 + l4) ^ (r & 7)) * 16));
      }
      __builtin_amdgcn_s_setprio(1);
#pragma unroll
      for (int fm = 0; fm < 4; ++fm)
#pragma unroll
        for (int fn = 0; fn < 4; ++fn)
          acc[fm][fn] = __builtin_amdgcn_mfma_f32_16x16x32_bf16(af[fm], bfr[fn], acc[fm][fn], 0, 0, 0);
      __builtin_amdgcn_s_setprio(0);
    }
    if (t + 1 < 16) writeB(cur ^ 1);   // cvt+write after compute: HBM latency hidden
    cur ^= 1;
  }

  // acc[fw][fx]: C row n = n0 + wr*64 + fw*16 + l4*4 + j (d); C col m = m0 + wc*64 + fx*16 + l15 (l)
  if (region < 2) {
    unsigned short* Out = (region == 0) ? Qp : Kp;
    const float scale = (region == 0) ? 0.18033688011112042f : 1.0f;  // 0.125 * log2(e)
#pragma unroll
    for (int fw = 0; fw < 4; ++fw) {
      int nb = n0 + wr * 64 + fw * 16 + l4 * 4;
      int h = nb >> 6, d0 = nb & 63;
      float4 bv4 = *reinterpret_cast<const float4*>(bias + nb);
#pragma unroll
      for (int fx = 0; fx < 4; ++fx) {
        int rowm = (m0 + wc * 64 + fx * 16 + l15) & 4095;
        int b = rowm >> 11, l = rowm & 2047;
        float v0 = (acc[fw][fx][0] + bv4.x) * scale;
        float v1 = (acc[fw][fx][1] + bv4.y) * scale;
        float v2 = (acc[fw][fx][2] + bv4.z) * scale;
        float v3 = (acc[fw][fx][3] + bv4.w) * scale;
        uint2 wv;
        wv.x = cvtpk_bf16(v0, v1);
        wv.y = cvtpk_bf16(v2, v3);
        *reinterpret_cast<uint2*>(Out + (((size_t)(b * 16 + h) * 2048 + l) << 6) + d0) = wv;
      }
    }
  } else {
#pragma unroll
    for (int fw = 0; fw < 4; ++fw) {
      int nb = n0 + wr * 64 + fw * 16 + l4 * 4;
      int h = nb >> 6, d0 = nb & 63;
      float4 bv4 = *reinterpret_cast<const float4*>(bias + nb);
#pragma unroll
      for (int fx = 0; fx < 4; ++fx) {
        int rowm = (m0 + wc * 64 + fx * 16 + l15) & 4095;
        int b = rowm >> 11, l = rowm & 2047;
        float g = gate[rowm];
        float vj[4] = {(acc[fw][fx][0] + bv4.x) * g, (acc[fw][fx][1] + bv4.y) * g,
                       (acc[fw][fx][2] + bv4.z) * g, (acc[fw][fx][3] + bv4.w) * g};
#pragma unroll
        for (int j = 0; j < 4; ++j)
          Vt[((size_t)(b * 16 + h) * 64 + d0 + j) * 2048 + l] = f2bf(vj[j]);
      }
    }
  }
}

// ---------------- O projection GEMM, operand-swapped, float4 stores ----------------
__global__ __launch_bounds__(256) void k_gemm_f32(const unsigned short* __restrict__ A,
                                                  const unsigned short* __restrict__ Bt,
                                                  const float* __restrict__ bias,
                                                  float* __restrict__ C) {
  __shared__ unsigned short sA[2][128 * 64];
  __shared__ unsigned short sB[2][128 * 64];
  const int tid = threadIdx.x;
  const int lane = tid & 63, wave = tid >> 6;
  const int l15 = lane & 15, l4 = lane >> 4;
  const int wr = wave >> 1, wc = wave & 1;
  const int m0 = blockIdx.x * 128, n0 = blockIdx.y * 128;

  const f32x4 zero4 = {0.f, 0.f, 0.f, 0.f};
  f32x4 acc[4][4];
#pragma unroll
  for (int i = 0; i < 4; ++i)
#pragma unroll
    for (int j = 0; j < 4; ++j) acc[i][j] = zero4;

  // W as A-operand, activations as B-operand
  gemm_tile<16>(Bt, A, &sA[0][0], &sB[0][0], n0, m0, tid, acc);

#pragma unroll
  for (int fw = 0; fw < 4; ++fw) {
    int col0 = n0 + wr * 64 + fw * 16 + l4 * 4;
    float4 bv4 = *reinterpret_cast<const float4*>(bias + col0);
#pragma unroll
    for (int fx = 0; fx < 4; ++fx) {
      int row = m0 + wc * 64 + fx * 16 + l15;
      float4 o;
      o.x = acc[fw][fx][0] + bv4.x;
      o.y = acc[fw][fx][1] + bv4.y;
      o.z = acc[fw][fx][2] + bv4.z;
      o.w = acc[fw][fx][3] + bv4.w;
      *reinterpret_cast<float4*>(C + (size_t)row * 1024 + col0) = o;
    }
  }
}

// ---------------- flash attention: swapped-QK, pi-permuted K staging, lane-local P ----------------
// 3-buffer LDS + ONE barrier per tile; counted vmcnt(4) keeps next-tile loads in flight.
// Softmax denominator via ones-MFMA (same lane/reg layout as accO -> zero-shuffle epilogue).
__global__ __launch_bounds__(256) void k_flash(const unsigned short* __restrict__ Qp,
                                               const unsigned short* __restrict__ Kp,
                                               const unsigned short* __restrict__ Vt,
                                               unsigned short* __restrict__ O) {
  __shared__ unsigned short sK[3][64 * 64];   // 24KB
  __shared__ unsigned short sV[3][64 * 64];   // 24KB (V^T: rows=d, cols=keys)
  const int tid = threadIdx.x;
  const int lane = tid & 63, wave = tid >> 6;
  const int l15 = lane & 15, l4 = lane >> 4;
  const int bh = blockIdx.x;
  const int q0 = blockIdx.y * 128;
  const int b = bh >> 4, h = bh & 15;
  const size_t hBase = (size_t)bh * 2048 * 64;
  const int wofs = (tid & 192) * 16;          // wave-uniform LDS offset

  // Q fragments (B-operand): col=q (l15), k-elems kc*32 + l4*8..+7. Q pre-scaled by 0.125*log2e.
  bf16x8 qf[2][2];
#pragma unroll
  for (int fq = 0; fq < 2; ++fq) {
    int qrow = q0 + wave * 32 + fq * 16 + l15;
#pragma unroll
    for (int kc = 0; kc < 2; ++kc)
      qf[fq][kc] = *reinterpret_cast<const bf16x8*>(Qp + hBase + (size_t)qrow * 64 + kc * 32 + l4 * 8);
  }

  // all-ones bf16 B-fragment for the denominator MFMA
  const short one_bf = 0x3F80;
  const bf16x8 ones = {one_bf, one_bf, one_bf, one_bf, one_bf, one_bf, one_bf, one_bf};

  const f32x4 zero4 = {0.f, 0.f, 0.f, 0.f};
  f32x4 accO[2][4];
  f32x4 accL[2];                  // row-sum accumulator (denominator), same layout as accO
#pragma unroll
  for (int fq = 0; fq < 2; ++fq) {
    accL[fq] = zero4;
#pragma unroll
    for (int fd = 0; fd < 4; ++fd) accO[fq][fd] = zero4;
  }

  auto stage = [&](int buf, int kv0) {
#pragma unroll
    for (int i = 0; i < 2; ++i) {
      int id = i * 256 + tid;
      int r = id >> 3, c = id & 7;
      int sc = (c ^ (r & 7)) << 3;
      int kr = (r & 32) | ((r & 12) << 1) | ((r & 16) >> 2) | (r & 3);  // pi^-1(r)
      GLD16(Kp + hBase + (size_t)(kv0 + kr) * 64 + sc, (char*)sK[buf] + i * 4096 + wofs);
      GLD16(Vt + hBase + (size_t)r * 2048 + kv0 + sc, (char*)sV[buf] + i * 4096 + wofs);
    }
  };

  auto tile = [&](int t, int cb, int sb, bool last, bool dostage) {
    if (last) { asm volatile("s_waitcnt vmcnt(0)" ::: "memory"); }
    else      { asm volatile("s_waitcnt vmcnt(4)" ::: "memory"); }
    __builtin_amdgcn_sched_barrier(0);
    __builtin_amdgcn_s_barrier();
    __builtin_amdgcn_sched_barrier(0);

    // S^T = K Q^T: s[fk][fq], C row = permuted-k (l4*4+j), col = q (l15)
    f32x4 s[4][2];
#pragma unroll
    for (int fk = 0; fk < 4; ++fk)
#pragma unroll
      for (int fq = 0; fq < 2; ++fq) s[fk][fq] = zero4;
#pragma unroll
    for (int kc = 0; kc < 2; ++kc) {
      bf16x8 kf[4];
#pragma unroll
      for (int fk = 0; fk < 4; ++fk) {
        int r = fk * 16 + l15;
        kf[fk] = *reinterpret_cast<const bf16x8*>(
            reinterpret_cast<const char*>(sK[cb]) + r * 128 + (((kc * 4 + l4) ^ (r & 7)) * 16));
      }
      __builtin_amdgcn_s_setprio(1);
#pragma unroll
      for (int fk = 0; fk < 4; ++fk)
#pragma unroll
        for (int fq = 0; fq < 2; ++fq)
          s[fk][fq] = __builtin_amdgcn_mfma_f32_16x16x32_bf16(kf[fk], qf[fq][kc], s[fk][fq], 0, 0, 0);
      __builtin_amdgcn_s_setprio(0);
    }

    if (dostage) stage(sb, (t + 2) * 64);

    // p = 2^s; lane-local A-fragments (pi-staging made k contiguous in-lane)
    u32x4 pfa[2][2];
#pragma unroll
    for (int fq = 0; fq < 2; ++fq) {
      float p[4][4];
#pragma unroll
      for (int fk = 0; fk < 4; ++fk)
#pragma unroll
        for (int j = 0; j < 4; ++j) p[fk][j] = fast_exp2(s[fk][fq][j]);
      pfa[fq][0].x = cvtpk_bf16(p[0][0], p[0][1]);
      pfa[fq][0].y = cvtpk_bf16(p[0][2], p[0][3]);
      pfa[fq][0].z = cvtpk_bf16(p[1][0], p[1][1]);
      pfa[fq][0].w = cvtpk_bf16(p[1][2], p[1][3]);
      pfa[fq][1].x = cvtpk_bf16(p[2][0], p[2][1]);
      pfa[fq][1].y = cvtpk_bf16(p[2][2], p[2][3]);
      pfa[fq][1].z = cvtpk_bf16(p[3][0], p[3][1]);
      pfa[fq][1].w = cvtpk_bf16(p[3][2], p[3][3]);
    }

    // O += P * V  (A = lane-local P, B = V^T rows d); denominator via ones-MFMA
#pragma unroll
    for (int kc = 0; kc < 2; ++kc) {
      bf16x8 vf[4];
#pragma unroll
      for (int fd = 0; fd < 4; ++fd) {
        int r = fd * 16 + l15;
        vf[fd] = *reinterpret_cast<const bf16x8*>(
            reinterpret_cast<const char*>(sV[cb]) + r * 128 + (((kc * 4 + l4) ^ (r & 7)) * 16));
      }
      __builtin_amdgcn_s_setprio(1);
#pragma unroll
      for (int fq = 0; fq < 2; ++fq) {
        bf16x8 pf = __builtin_bit_cast(bf16x8, pfa[fq][kc]);
#pragma unroll
        for (int fd = 0; fd < 4; ++fd)
          accO[fq][fd] = __builtin_amdgcn_mfma_f32_16x16x32_bf16(pf, vf[fd], accO[fq][fd], 0, 0, 0);
        accL[fq] = __builtin_amdgcn_mfma_f32_16x16x32_bf16(pf, ones, accL[fq], 0, 0, 0);
      }
      __builtin_amdgcn_s_setprio(0);
    }
  };

  stage(0, 0);
  stage(1, 64);

  for (int base = 0; base < 30; base += 3) {
    tile(base + 0, 0, 2, false, true);
    tile(base + 1, 1, 0, false, true);
    tile(base + 2, 2, 1, false, true);
  }
  tile(30, 0, 2, false, false);
  tile(31, 1, 0, true, false);

  // epilogue: denominator already in matching lane/reg layout -> divide and store bf16
#pragma unroll
  for (int fq = 0; fq < 2; ++fq)
#pragma unroll
    for (int j = 0; j < 4; ++j) {
      float li = 1.0f / accL[fq][j];
      int qw = q0 + wave * 32 + fq * 16 + l4 * 4 + j;
#pragma unroll
      for (int fd = 0; fd < 4; ++fd) {
        int col = h * 64 + fd * 16 + l15;
        O[(size_t)(b * 2048 + qw) * 1024 + col] = f2bf(accO[fq][fd][j] * li);
      }
    }
}

extern "C" void kernel_launch(void* const* d_in, const int* in_sizes, int n_in,
                              void* d_out, int out_size, void* d_ws, size_t ws_size,
                              hipStream_t stream) {
  const float* q_x = (const float*)d_in[0];
  const float* k_x = (const float*)d_in[1];
  const float* v_x = (const float*)d_in[2];
  const float* E   = (const float*)d_in[3];
  const float* Wq  = (const float*)d_in[4];
  const float* bq  = (const float*)d_in[5];
  const float* Wk  = (const float*)d_in[6];
  const float* bk  = (const float*)d_in[7];
  const float* Wv  = (const float*)d_in[8];
  const float* bv  = (const float*)d_in[9];
  const float* Wo  = (const float*)d_in[10];
  const float* bo  = (const float*)d_in[11];
  float* out = (float*)d_out;

  char* w = (char*)d_ws;
  unsigned short* Wt4  = (unsigned short*)(w + 0);          // 4x 1024x1024 bf16 = 8 MB (Q,K,V,O)
  unsigned short* Whq  = Wt4;
  unsigned short* Whk  = Wt4 + 1048576;
  unsigned short* Wtv  = Wt4 + 2097152;
  unsigned short* Wto  = Wt4 + 3145728;
  unsigned short* Qp   = (unsigned short*)(w + 8388608);    // 8 MB
  unsigned short* Kpp  = (unsigned short*)(w + 16777216);   // 8 MB
  unsigned short* Vtp  = (unsigned short*)(w + 25165824);   // 8 MB
  unsigned short* Obf  = (unsigned short*)(w + 33554432);   // 8 MB
  float*          gate = (float*)(w + 41943040);            // 16 KB

  k_gate<<<16, 256, 0, stream>>>(E, gate);

  // all 4 weight transposes in one dispatch
  k_pack_wT4<<<dim3(32, 32, 4), 256, 0, stream>>>(Wq, Wk, Wv, Wo, Wt4);

  // fused Q+K+V projections straight from f32 inputs (no X pack pass)
  k_gemm_qkv<<<dim3(96, 8), 256, 0, stream>>>(q_x, k_x, v_x, Whq, Whk, Wtv,
                                              bq, bk, bv, gate, Qp, Kpp, Vtp);

  // attention -> bf16 (b,l,1024)
  k_flash<<<dim3(32, 16), 256, 0, stream>>>(Qp, Kpp, Vtp, Obf);

  // output projection
  k_gemm_f32<<<dim3(32, 8), 256, 0, stream>>>(Obf, Wto, bo, out);
}

// Round 17
// 124.043 us; speedup vs baseline: 1.1498x; 1.1498x over previous
//
#include <hip/hip_runtime.h>

typedef __attribute__((ext_vector_type(8))) short bf16x8;
typedef __attribute__((ext_vector_type(8))) unsigned short u16x8;
typedef __attribute__((ext_vector_type(4))) float f32x4;
typedef __attribute__((ext_vector_type(4))) unsigned int u32x4;

#define DEVI static __device__ __forceinline__

// async global->LDS, 16B per lane; gp per-lane, lp wave-uniform
typedef const __attribute__((address_space(1))) void cglobal_void;
typedef __attribute__((address_space(3))) void lds_void;
#define GLD16(gp, lp) __builtin_amdgcn_global_load_lds((cglobal_void*)(gp), (lds_void*)(lp), 16, 0, 0)

DEVI unsigned short f2bf(float x) {
  unsigned int u = __builtin_bit_cast(unsigned int, x);
  u += 0x7fffu + ((u >> 16) & 1u);   // round-to-nearest-even
  return (unsigned short)(u >> 16);
}
// hardware packed f32x2 -> bf16x2 (RNE), single VALU op
DEVI unsigned int cvtpk_bf16(float lo, float hi) {
  unsigned int r;
  asm("v_cvt_pk_bf16_f32 %0, %1, %2" : "=v"(r) : "v"(lo), "v"(hi));
  return r;
}
// raw v_exp_f32 (2^x), no libm guard sequence
DEVI float fast_exp2(float x) {
  float r;
  asm("v_exp_f32 %0, %1" : "=v"(r) : "v"(x));
  return r;
}

// ---------------- gate: sigmoid((mean|E| - 0.1)*10) per (b,l) key ----------------
__global__ void k_gate(const float* __restrict__ E, float* __restrict__ gate) {
  int i = blockIdx.x * 256 + threadIdx.x;           // 0..4095
  const float4* e = reinterpret_cast<const float4*>(E);
  float4 a = e[i * 2], b = e[i * 2 + 1];
  float s = fabsf(a.x) + fabsf(a.y) + fabsf(a.z) + fabsf(a.w)
          + fabsf(b.x) + fabsf(b.y) + fabsf(b.z) + fabsf(b.w);
  float en = s * 0.125f;
  gate[i] = 1.0f / (1.0f + __expf(-10.0f * (en - 0.1f)));
}

// ---------------- pack q_x/k_x/v_x (each 4096x1024 f32) -> stacked bf16 (y selects) ----------------
__global__ void k_pack_plain3(const float* __restrict__ X0, const float* __restrict__ X1,
                              const float* __restrict__ X2, unsigned short* __restrict__ Xp) {
  const float* X = (blockIdx.y == 0) ? X0 : (blockIdx.y == 1) ? X1 : X2;
  int t = blockIdx.x * 256 + threadIdx.x;
  int idx = t << 3;
  const float4* src = reinterpret_cast<const float4*>(X + idx);
  float4 a = src[0], b = src[1];
  float xs[8] = {a.x, a.y, a.z, a.w, b.x, b.y, b.z, b.w};
  u16x8 hi;
#pragma unroll
  for (int j = 0; j < 8; ++j) hi[j] = f2bf(xs[j]);
  *reinterpret_cast<u16x8*>(Xp + (size_t)blockIdx.y * 4194304 + idx) = hi;
}

// ---------------- pack 4x W (1024x1024) -> transposed bf16 (z selects) ----------------
__global__ void k_pack_wT4(const float* __restrict__ W0, const float* __restrict__ W1,
                           const float* __restrict__ W2, const float* __restrict__ W3,
                           unsigned short* __restrict__ Wt) {
  const float* W = (blockIdx.z == 0) ? W0 : (blockIdx.z == 1) ? W1
                 : (blockIdx.z == 2) ? W2 : W3;
  unsigned short* D = Wt + (size_t)blockIdx.z * 1048576;
  __shared__ float tile[32][33];
  int tx = threadIdx.x & 31, ty = threadIdx.x >> 5;
  int kb = blockIdx.x * 32, nb = blockIdx.y * 32;
#pragma unroll
  for (int i = 0; i < 4; ++i)
    tile[ty + 8 * i][tx] = W[(size_t)(kb + ty + 8 * i) * 1024 + nb + tx];
  __syncthreads();
#pragma unroll
  for (int i = 0; i < 4; ++i) {
    int n = nb + ty + 8 * i;
    int k = kb + tx;
    D[(size_t)n * 1024 + k] = f2bf(tile[tx][ty + 8 * i]);
  }
}

// ---------------- GEMM main loop: 128x128 tile, BK=32, 3-buffer LDS, counted-vmcnt schedule -------
// Per buffer: sA/sB 128 rows x 32 bf16 (64B rows, 4 chunks). Chunk c of row r stored at chunk
// c ^ ((r>>1)&3) (round-14-verified swizzle; read cq = l4 ^ ((l15>>1)&3), row-independent).
// Schedule (flash-proven): top of step t: wait vmcnt(4) (stage t+1 stays in flight) + raw
// barrier; read+MFMA buf t%3; issue stage (t+2)%3 after the barrier -> write-after-read safe
// (buf last read at t-1, all waves past barrier). LDS 48KB -> 3 blocks/CU, grid 768 = 3x256.
DEVI void gemm_tile3(const unsigned short* __restrict__ A,
                     const unsigned short* __restrict__ Bt,
                     unsigned short* sA0, unsigned short* sB0,
                     int m0, int n0, int tid, f32x4 acc[4][4]) {
  const int lane = tid & 63;
  const int l15 = lane & 15, l4 = lane >> 4;
  const int wave = tid >> 6;
  const int wr = wave >> 1, wc = wave & 1;
  const int wofs = (tid & 192) * 16;              // wave-uniform LDS base offset
  const int cq = (l4 ^ ((l15 >> 1) & 3)) << 4;    // swizzled chunk byte offset (row-indep)

  auto stage = [&](int buf, int k0) {
    unsigned short* dA = sA0 + buf * 4096;        // 8KB per buffer
    unsigned short* dB = sB0 + buf * 4096;
#pragma unroll
    for (int i = 0; i < 2; ++i) {
      int id = i * 256 + tid;
      int r = id >> 2, c = id & 3;
      int sc = (c ^ ((r >> 1) & 3)) << 3;
      GLD16(A + (size_t)(m0 + r) * 1024 + k0 + sc, (char*)dA + i * 4096 + wofs);
    }
#pragma unroll
    for (int i = 0; i < 2; ++i) {
      int id = i * 256 + tid;
      int r = id >> 2, c = id & 3;
      int sc = (c ^ ((r >> 1) & 3)) << 3;
      GLD16(Bt + (size_t)(n0 + r) * 1024 + k0 + sc, (char*)dB + i * 4096 + wofs);
    }
  };

  stage(0, 0);
  stage(1, 32);

  for (int t = 0; t < 32; ++t) {
    const int cb = t % 3;
    if (t < 31) asm volatile("s_waitcnt vmcnt(4)" ::: "memory");
    else        asm volatile("s_waitcnt vmcnt(0)" ::: "memory");
    __builtin_amdgcn_sched_barrier(0);
    __builtin_amdgcn_s_barrier();
    __builtin_amdgcn_sched_barrier(0);

    const unsigned short* cA = sA0 + cb * 4096;
    const unsigned short* cB = sB0 + cb * 4096;
    bf16x8 af[4], bfr[4];
#pragma unroll
    for (int f = 0; f < 4; ++f) {
      int r = wr * 64 + f * 16 + l15;
      af[f] = *reinterpret_cast<const bf16x8*>(reinterpret_cast<const char*>(cA) + r * 64 + cq);
    }
#pragma unroll
    for (int f = 0; f < 4; ++f) {
      int r = wc * 64 + f * 16 + l15;
      bfr[f] = *reinterpret_cast<const bf16x8*>(reinterpret_cast<const char*>(cB) + r * 64 + cq);
    }

    if (t + 2 < 32) stage((t + 2) % 3, (t + 2) * 32);

    __builtin_amdgcn_s_setprio(1);
#pragma unroll
    for (int fm = 0; fm < 4; ++fm)
#pragma unroll
      for (int fn = 0; fn < 4; ++fn)
        acc[fm][fn] = __builtin_amdgcn_mfma_f32_16x16x32_bf16(af[fm], bfr[fn], acc[fm][fn], 0, 0, 0);
    __builtin_amdgcn_s_setprio(0);
  }
}

// ---------------- fused Q+K+V projection GEMM (M=12288 stacked bf16, K=1024) ----------------
// Operand-swapped: W = A (rows = d), X = B (rows = l) -> C rows = d -> vectorized 8B stores.
// Region by blockIdx.x: 0=Q (scaled 0.125*log2e), 1=K, 2=V (gated, per-head transposed).
__global__ __launch_bounds__(256) void k_gemm_qkv(const unsigned short* __restrict__ Xqkv,
                                                  const unsigned short* __restrict__ WhQ,
                                                  const unsigned short* __restrict__ WhK,
                                                  const unsigned short* __restrict__ WhV,
                                                  const float* __restrict__ bq,
                                                  const float* __restrict__ bk,
                                                  const float* __restrict__ bv,
                                                  const float* __restrict__ gate,
                                                  unsigned short* __restrict__ Qp,
                                                  unsigned short* __restrict__ Kp,
                                                  unsigned short* __restrict__ Vt) {
  __shared__ unsigned short sA[3][128 * 32];   // 24KB (W tiles)
  __shared__ unsigned short sB[3][128 * 32];   // 24KB (X tiles)
  const int tid = threadIdx.x;
  const int lane = tid & 63, wave = tid >> 6;
  const int l15 = lane & 15, l4 = lane >> 4;
  const int wr = wave >> 1, wc = wave & 1;
  const int m0 = blockIdx.x * 128, n0 = blockIdx.y * 128;
  const int region = m0 >> 12;                 // 0=Q, 1=K, 2=V
  const unsigned short* Wm = (region == 0) ? WhQ : (region == 1) ? WhK : WhV;
  const float* bias = (region == 0) ? bq : (region == 1) ? bk : bv;

  const f32x4 zero4 = {0.f, 0.f, 0.f, 0.f};
  f32x4 acc[4][4];
#pragma unroll
  for (int i = 0; i < 4; ++i)
#pragma unroll
    for (int j = 0; j < 4; ++j) acc[i][j] = zero4;

  // W as A-operand (rows = d dim), X as B-operand (rows = l dim)
  gemm_tile3(Wm, Xqkv, &sA[0][0], &sB[0][0], n0, m0, tid, acc);

  // acc[fw][fx]: C row n = n0 + wr*64 + fw*16 + l4*4 + j (d); C col m = m0 + wc*64 + fx*16 + l15 (l)
  if (region < 2) {
    unsigned short* Out = (region == 0) ? Qp : Kp;
    const float scale = (region == 0) ? 0.18033688011112042f : 1.0f;  // 0.125 * log2(e)
#pragma unroll
    for (int fw = 0; fw < 4; ++fw) {
      int nb = n0 + wr * 64 + fw * 16 + l4 * 4;
      int h = nb >> 6, d0 = nb & 63;
      float4 bv4 = *reinterpret_cast<const float4*>(bias + nb);
#pragma unroll
      for (int fx = 0; fx < 4; ++fx) {
        int rowm = (m0 + wc * 64 + fx * 16 + l15) & 4095;
        int b = rowm >> 11, l = rowm & 2047;
        float v0 = (acc[fw][fx][0] + bv4.x) * scale;
        float v1 = (acc[fw][fx][1] + bv4.y) * scale;
        float v2 = (acc[fw][fx][2] + bv4.z) * scale;
        float v3 = (acc[fw][fx][3] + bv4.w) * scale;
        uint2 wv;
        wv.x = cvtpk_bf16(v0, v1);
        wv.y = cvtpk_bf16(v2, v3);
        *reinterpret_cast<uint2*>(Out + (((size_t)(b * 16 + h) * 2048 + l) << 6) + d0) = wv;
      }
    }
  } else {
#pragma unroll
    for (int fw = 0; fw < 4; ++fw) {
      int nb = n0 + wr * 64 + fw * 16 + l4 * 4;
      int h = nb >> 6, d0 = nb & 63;
      float4 bv4 = *reinterpret_cast<const float4*>(bias + nb);
#pragma unroll
      for (int fx = 0; fx < 4; ++fx) {
        int rowm = (m0 + wc * 64 + fx * 16 + l15) & 4095;
        int b = rowm >> 11, l = rowm & 2047;
        float g = gate[rowm];
        float vj[4] = {(acc[fw][fx][0] + bv4.x) * g, (acc[fw][fx][1] + bv4.y) * g,
                       (acc[fw][fx][2] + bv4.z) * g, (acc[fw][fx][3] + bv4.w) * g};
#pragma unroll
        for (int j = 0; j < 4; ++j)
          Vt[((size_t)(b * 16 + h) * 64 + d0 + j) * 2048 + l] = f2bf(vj[j]);
      }
    }
  }
}

// ---------------- O projection GEMM, operand-swapped, float4 stores ----------------
__global__ __launch_bounds__(256) void k_gemm_f32(const unsigned short* __restrict__ A,
                                                  const unsigned short* __restrict__ Bt,
                                                  const float* __restrict__ bias,
                                                  float* __restrict__ C) {
  __shared__ unsigned short sA[3][128 * 32];
  __shared__ unsigned short sB[3][128 * 32];
  const int tid = threadIdx.x;
  const int lane = tid & 63, wave = tid >> 6;
  const int l15 = lane & 15, l4 = lane >> 4;
  const int wr = wave >> 1, wc = wave & 1;
  const int m0 = blockIdx.x * 128, n0 = blockIdx.y * 128;

  const f32x4 zero4 = {0.f, 0.f, 0.f, 0.f};
  f32x4 acc[4][4];
#pragma unroll
  for (int i = 0; i < 4; ++i)
#pragma unroll
    for (int j = 0; j < 4; ++j) acc[i][j] = zero4;

  // W as A-operand, activations as B-operand
  gemm_tile3(Bt, A, &sA[0][0], &sB[0][0], n0, m0, tid, acc);

#pragma unroll
  for (int fw = 0; fw < 4; ++fw) {
    int col0 = n0 + wr * 64 + fw * 16 + l4 * 4;
    float4 bv4 = *reinterpret_cast<const float4*>(bias + col0);
#pragma unroll
    for (int fx = 0; fx < 4; ++fx) {
      int row = m0 + wc * 64 + fx * 16 + l15;
      float4 o;
      o.x = acc[fw][fx][0] + bv4.x;
      o.y = acc[fw][fx][1] + bv4.y;
      o.z = acc[fw][fx][2] + bv4.z;
      o.w = acc[fw][fx][3] + bv4.w;
      *reinterpret_cast<float4*>(C + (size_t)row * 1024 + col0) = o;
    }
  }
}

// ---------------- flash attention: swapped-QK, pi-permuted K staging, lane-local P ----------------
// 3-buffer LDS + ONE barrier per tile; counted vmcnt(4) keeps next-tile loads in flight.
// Softmax denominator via ones-MFMA (same lane/reg layout as accO -> zero-shuffle epilogue).
__global__ __launch_bounds__(256) void k_flash(const unsigned short* __restrict__ Qp,
                                               const unsigned short* __restrict__ Kp,
                                               const unsigned short* __restrict__ Vt,
                                               unsigned short* __restrict__ O) {
  __shared__ unsigned short sK[3][64 * 64];   // 24KB
  __shared__ unsigned short sV[3][64 * 64];   // 24KB (V^T: rows=d, cols=keys)
  const int tid = threadIdx.x;
  const int lane = tid & 63, wave = tid >> 6;
  const int l15 = lane & 15, l4 = lane >> 4;
  const int bh = blockIdx.x;
  const int q0 = blockIdx.y * 128;
  const int b = bh >> 4, h = bh & 15;
  const size_t hBase = (size_t)bh * 2048 * 64;
  const int wofs = (tid & 192) * 16;          // wave-uniform LDS offset

  // Q fragments (B-operand): col=q (l15), k-elems kc*32 + l4*8..+7. Q pre-scaled by 0.125*log2e.
  bf16x8 qf[2][2];
#pragma unroll
  for (int fq = 0; fq < 2; ++fq) {
    int qrow = q0 + wave * 32 + fq * 16 + l15;
#pragma unroll
    for (int kc = 0; kc < 2; ++kc)
      qf[fq][kc] = *reinterpret_cast<const bf16x8*>(Qp + hBase + (size_t)qrow * 64 + kc * 32 + l4 * 8);
  }

  // all-ones bf16 B-fragment for the denominator MFMA
  const short one_bf = 0x3F80;
  const bf16x8 ones = {one_bf, one_bf, one_bf, one_bf, one_bf, one_bf, one_bf, one_bf};

  const f32x4 zero4 = {0.f, 0.f, 0.f, 0.f};
  f32x4 accO[2][4];
  f32x4 accL[2];                  // row-sum accumulator (denominator), same layout as accO
#pragma unroll
  for (int fq = 0; fq < 2; ++fq) {
    accL[fq] = zero4;
#pragma unroll
    for (int fd = 0; fd < 4; ++fd) accO[fq][fd] = zero4;
  }

  auto stage = [&](int buf, int kv0) {
#pragma unroll
    for (int i = 0; i < 2; ++i) {
      int id = i * 256 + tid;
      int r = id >> 3, c = id & 7;
      int sc = (c ^ (r & 7)) << 3;
      int kr = (r & 32) | ((r & 12) << 1) | ((r & 16) >> 2) | (r & 3);  // pi^-1(r)
      GLD16(Kp + hBase + (size_t)(kv0 + kr) * 64 + sc, (char*)sK[buf] + i * 4096 + wofs);
      GLD16(Vt + hBase + (size_t)r * 2048 + kv0 + sc, (char*)sV[buf] + i * 4096 + wofs);
    }
  };

  auto tile = [&](int t, int cb, int sb, bool last, bool dostage) {
    if (last) { asm volatile("s_waitcnt vmcnt(0)" ::: "memory"); }
    else      { asm volatile("s_waitcnt vmcnt(4)" ::: "memory"); }
    __builtin_amdgcn_sched_barrier(0);
    __builtin_amdgcn_s_barrier();
    __builtin_amdgcn_sched_barrier(0);

    // S^T = K Q^T: s[fk][fq], C row = permuted-k (l4*4+j), col = q (l15)
    f32x4 s[4][2];
#pragma unroll
    for (int fk = 0; fk < 4; ++fk)
#pragma unroll
      for (int fq = 0; fq < 2; ++fq) s[fk][fq] = zero4;
#pragma unroll
    for (int kc = 0; kc < 2; ++kc) {
      bf16x8 kf[4];
#pragma unroll
      for (int fk = 0; fk < 4; ++fk) {
        int r = fk * 16 + l15;
        kf[fk] = *reinterpret_cast<const bf16x8*>(
            reinterpret_cast<const char*>(sK[cb]) + r * 128 + (((kc * 4 + l4) ^ (r & 7)) * 16));
      }
      __builtin_amdgcn_s_setprio(1);
#pragma unroll
      for (int fk = 0; fk < 4; ++fk)
#pragma unroll
        for (int fq = 0; fq < 2; ++fq)
          s[fk][fq] = __builtin_amdgcn_mfma_f32_16x16x32_bf16(kf[fk], qf[fq][kc], s[fk][fq], 0, 0, 0);
      __builtin_amdgcn_s_setprio(0);
    }

    if (dostage) stage(sb, (t + 2) * 64);

    // p = 2^s; lane-local A-fragments (pi-staging made k contiguous in-lane)
    u32x4 pfa[2][2];
#pragma unroll
    for (int fq = 0; fq < 2; ++fq) {
      float p[4][4];
#pragma unroll
      for (int fk = 0; fk < 4; ++fk)
#pragma unroll
        for (int j = 0; j < 4; ++j) p[fk][j] = fast_exp2(s[fk][fq][j]);
      pfa[fq][0].x = cvtpk_bf16(p[0][0], p[0][1]);
      pfa[fq][0].y = cvtpk_bf16(p[0][2], p[0][3]);
      pfa[fq][0].z = cvtpk_bf16(p[1][0], p[1][1]);
      pfa[fq][0].w = cvtpk_bf16(p[1][2], p[1][3]);
      pfa[fq][1].x = cvtpk_bf16(p[2][0], p[2][1]);
      pfa[fq][1].y = cvtpk_bf16(p[2][2], p[2][3]);
      pfa[fq][1].z = cvtpk_bf16(p[3][0], p[3][1]);
      pfa[fq][1].w = cvtpk_bf16(p[3][2], p[3][3]);
    }

    // O += P * V  (A = lane-local P, B = V^T rows d); denominator via ones-MFMA
#pragma unroll
    for (int kc = 0; kc < 2; ++kc) {
      bf16x8 vf[4];
#pragma unroll
      for (int fd = 0; fd < 4; ++fd) {
        int r = fd * 16 + l15;
        vf[fd] = *reinterpret_cast<const bf16x8*>(
            reinterpret_cast<const char*>(sV[cb]) + r * 128 + (((kc * 4 + l4) ^ (r & 7)) * 16));
      }
      __builtin_amdgcn_s_setprio(1);
#pragma unroll
      for (int fq = 0; fq < 2; ++fq) {
        bf16x8 pf = __builtin_bit_cast(bf16x8, pfa[fq][kc]);
#pragma unroll
        for (int fd = 0; fd < 4; ++fd)
          accO[fq][fd] = __builtin_amdgcn_mfma_f32_16x16x32_bf16(pf, vf[fd], accO[fq][fd], 0, 0, 0);
        accL[fq] = __builtin_amdgcn_mfma_f32_16x16x32_bf16(pf, ones, accL[fq], 0, 0, 0);
      }
      __builtin_amdgcn_s_setprio(0);
    }
  };

  stage(0, 0);
  stage(1, 64);

  for (int base = 0; base < 30; base += 3) {
    tile(base + 0, 0, 2, false, true);
    tile(base + 1, 1, 0, false, true);
    tile(base + 2, 2, 1, false, true);
  }
  tile(30, 0, 2, false, false);
  tile(31, 1, 0, true, false);

  // epilogue: denominator already in matching lane/reg layout -> divide and store bf16
#pragma unroll
  for (int fq = 0; fq < 2; ++fq)
#pragma unroll
    for (int j = 0; j < 4; ++j) {
      float li = 1.0f / accL[fq][j];
      int qw = q0 + wave * 32 + fq * 16 + l4 * 4 + j;
#pragma unroll
      for (int fd = 0; fd < 4; ++fd) {
        int col = h * 64 + fd * 16 + l15;
        O[(size_t)(b * 2048 + qw) * 1024 + col] = f2bf(accO[fq][fd][j] * li);
      }
    }
}

extern "C" void kernel_launch(void* const* d_in, const int* in_sizes, int n_in,
                              void* d_out, int out_size, void* d_ws, size_t ws_size,
                              hipStream_t stream) {
  const float* q_x = (const float*)d_in[0];
  const float* k_x = (const float*)d_in[1];
  const float* v_x = (const float*)d_in[2];
  const float* E   = (const float*)d_in[3];
  const float* Wq  = (const float*)d_in[4];
  const float* bq  = (const float*)d_in[5];
  const float* Wk  = (const float*)d_in[6];
  const float* bk  = (const float*)d_in[7];
  const float* Wv  = (const float*)d_in[8];
  const float* bv  = (const float*)d_in[9];
  const float* Wo  = (const float*)d_in[10];
  const float* bo  = (const float*)d_in[11];
  float* out = (float*)d_out;

  char* w = (char*)d_ws;
  unsigned short* Wt4  = (unsigned short*)(w + 0);          // 4x 1024x1024 bf16 = 8 MB (Q,K,V,O)
  unsigned short* Whq  = Wt4;
  unsigned short* Whk  = Wt4 + 1048576;
  unsigned short* Wtv  = Wt4 + 2097152;
  unsigned short* Wto  = Wt4 + 3145728;
  unsigned short* Xqkv = (unsigned short*)(w + 8388608);    // 12288x1024 bf16 = 24 MB
  unsigned short* Qp   = (unsigned short*)(w + 33554432);   // 8 MB
  unsigned short* Kpp  = (unsigned short*)(w + 41943040);   // 8 MB
  unsigned short* Vtp  = (unsigned short*)(w + 50331648);   // 8 MB
  unsigned short* Obf  = (unsigned short*)(w + 58720256);   // 8 MB
  float*          gate = (float*)(w + 67108864);            // 16 KB

  k_gate<<<16, 256, 0, stream>>>(E, gate);

  // all 4 weight transposes in one dispatch
  k_pack_wT4<<<dim3(32, 32, 4), 256, 0, stream>>>(Wq, Wk, Wv, Wo, Wt4);

  // Q, K, V inputs packed plain bf16, stacked along M (12288 rows), one dispatch
  k_pack_plain3<<<dim3(2048, 3), 256, 0, stream>>>(q_x, k_x, v_x, Xqkv);

  // fused Q+K+V projections: per-head bf16 epilogues (Q scaled; V gated+transposed)
  k_gemm_qkv<<<dim3(96, 8), 256, 0, stream>>>(Xqkv, Whq, Whk, Wtv, bq, bk, bv, gate,
                                              Qp, Kpp, Vtp);

  // attention -> bf16 (b,l,1024)
  k_flash<<<dim3(32, 16), 256, 0, stream>>>(Qp, Kpp, Vtp, Obf);

  // output projection
  k_gemm_f32<<<dim3(32, 8), 256, 0, stream>>>(Obf, Wto, bo, out);
}

// Round 18
// 123.464 us; speedup vs baseline: 1.1552x; 1.0047x over previous
//
#include <hip/hip_runtime.h>

typedef __attribute__((ext_vector_type(8))) short bf16x8;
typedef __attribute__((ext_vector_type(8))) unsigned short u16x8;
typedef __attribute__((ext_vector_type(4))) float f32x4;
typedef __attribute__((ext_vector_type(4))) unsigned int u32x4;

#define DEVI static __device__ __forceinline__

// async global->LDS, 16B per lane; gp per-lane, lp wave-uniform
typedef const __attribute__((address_space(1))) void cglobal_void;
typedef __attribute__((address_space(3))) void lds_void;
#define GLD16(gp, lp) __builtin_amdgcn_global_load_lds((cglobal_void*)(gp), (lds_void*)(lp), 16, 0, 0)

DEVI unsigned short f2bf(float x) {
  unsigned int u = __builtin_bit_cast(unsigned int, x);
  u += 0x7fffu + ((u >> 16) & 1u);   // round-to-nearest-even
  return (unsigned short)(u >> 16);
}
// hardware packed f32x2 -> bf16x2 (RNE), single VALU op
DEVI unsigned int cvtpk_bf16(float lo, float hi) {
  unsigned int r;
  asm("v_cvt_pk_bf16_f32 %0, %1, %2" : "=v"(r) : "v"(lo), "v"(hi));
  return r;
}
// raw v_exp_f32 (2^x), no libm guard sequence
DEVI float fast_exp2(float x) {
  float r;
  asm("v_exp_f32 %0, %1" : "=v"(r) : "v"(x));
  return r;
}

// ---------------- gate: sigmoid((mean|E| - 0.1)*10) per (b,l) key ----------------
__global__ void k_gate(const float* __restrict__ E, float* __restrict__ gate) {
  int i = blockIdx.x * 256 + threadIdx.x;           // 0..4095
  const float4* e = reinterpret_cast<const float4*>(E);
  float4 a = e[i * 2], b = e[i * 2 + 1];
  float s = fabsf(a.x) + fabsf(a.y) + fabsf(a.z) + fabsf(a.w)
          + fabsf(b.x) + fabsf(b.y) + fabsf(b.z) + fabsf(b.w);
  float en = s * 0.125f;
  gate[i] = 1.0f / (1.0f + __expf(-10.0f * (en - 0.1f)));
}

// ---------------- pack q_x/k_x/v_x (each 4096x1024 f32) -> stacked bf16 (y selects) ----------------
__global__ void k_pack_plain3(const float* __restrict__ X0, const float* __restrict__ X1,
                              const float* __restrict__ X2, unsigned short* __restrict__ Xp) {
  const float* X = (blockIdx.y == 0) ? X0 : (blockIdx.y == 1) ? X1 : X2;
  int t = blockIdx.x * 256 + threadIdx.x;
  int idx = t << 3;
  const float4* src = reinterpret_cast<const float4*>(X + idx);
  float4 a = src[0], b = src[1];
  float xs[8] = {a.x, a.y, a.z, a.w, b.x, b.y, b.z, b.w};
  u16x8 hi;
#pragma unroll
  for (int j = 0; j < 8; ++j) hi[j] = f2bf(xs[j]);
  *reinterpret_cast<u16x8*>(Xp + (size_t)blockIdx.y * 4194304 + idx) = hi;
}

// ---------------- pack 4x W (1024x1024) -> transposed bf16 (z selects) ----------------
__global__ void k_pack_wT4(const float* __restrict__ W0, const float* __restrict__ W1,
                           const float* __restrict__ W2, const float* __restrict__ W3,
                           unsigned short* __restrict__ Wt) {
  const float* W = (blockIdx.z == 0) ? W0 : (blockIdx.z == 1) ? W1
                 : (blockIdx.z == 2) ? W2 : W3;
  unsigned short* D = Wt + (size_t)blockIdx.z * 1048576;
  __shared__ float tile[32][33];
  int tx = threadIdx.x & 31, ty = threadIdx.x >> 5;
  int kb = blockIdx.x * 32, nb = blockIdx.y * 32;
#pragma unroll
  for (int i = 0; i < 4; ++i)
    tile[ty + 8 * i][tx] = W[(size_t)(kb + ty + 8 * i) * 1024 + nb + tx];
  __syncthreads();
#pragma unroll
  for (int i = 0; i < 4; ++i) {
    int n = nb + ty + 8 * i;
    int k = kb + tx;
    D[(size_t)n * 1024 + k] = f2bf(tile[tx][ty + 8 * i]);
  }
}

// ---------------- GEMM main loop: 128x128 tile, BK=32, FOUR LDS buffers, 3-deep prefetch ----------
// Per buffer: sA/sB 128 rows x 32 bf16 (64B rows, 4 chunks); chunk c of row r at c ^ ((r>>1)&3);
// read cq = l4 ^ ((l15>>1)&3) (row-independent, conflict-free; round-14-verified swizzle).
// Schedule: prologue stages 0,1,2. Iter t: wait vmcnt(8) (stages t+1,t+2 = 8 loads/thread stay in
// flight -> ~3 steps of HBM-latency cover) + ONE raw barrier; read frags buf t&3; issue stage
// t+3 into buf (t+3)&3 (holds stage t-1: its ds_reads fed iter t-1's MFMAs, complete before every
// wave reached barrier t -> write-after-read safe); MFMA. Tail: vmcnt(4) @ t=30, vmcnt(0) @ t=31.
DEVI void gemm_tile4(const unsigned short* __restrict__ A,
                     const unsigned short* __restrict__ Bt,
                     unsigned short* sA0, unsigned short* sB0,
                     int m0, int n0, int tid, f32x4 acc[4][4]) {
  const int lane = tid & 63;
  const int l15 = lane & 15, l4 = lane >> 4;
  const int wave = tid >> 6;
  const int wr = wave >> 1, wc = wave & 1;
  const int wofs = (tid & 192) * 16;              // wave-uniform LDS base offset
  const int cq = (l4 ^ ((l15 >> 1) & 3)) << 4;    // swizzled chunk byte offset (row-indep)

  auto stage = [&](int buf, int k0) {
    unsigned short* dA = sA0 + buf * 4096;        // 8KB per buffer
    unsigned short* dB = sB0 + buf * 4096;
#pragma unroll
    for (int i = 0; i < 2; ++i) {
      int id = i * 256 + tid;
      int r = id >> 2, c = id & 3;
      int sc = (c ^ ((r >> 1) & 3)) << 3;
      GLD16(A + (size_t)(m0 + r) * 1024 + k0 + sc, (char*)dA + i * 4096 + wofs);
    }
#pragma unroll
    for (int i = 0; i < 2; ++i) {
      int id = i * 256 + tid;
      int r = id >> 2, c = id & 3;
      int sc = (c ^ ((r >> 1) & 3)) << 3;
      GLD16(Bt + (size_t)(n0 + r) * 1024 + k0 + sc, (char*)dB + i * 4096 + wofs);
    }
  };

  stage(0, 0);
  stage(1, 32);
  stage(2, 64);

  for (int t = 0; t < 32; ++t) {
    const int cb = t & 3;
    if (t < 30)       asm volatile("s_waitcnt vmcnt(8)" ::: "memory");
    else if (t == 30) asm volatile("s_waitcnt vmcnt(4)" ::: "memory");
    else              asm volatile("s_waitcnt vmcnt(0)" ::: "memory");
    __builtin_amdgcn_sched_barrier(0);
    __builtin_amdgcn_s_barrier();
    __builtin_amdgcn_sched_barrier(0);

    const unsigned short* cA = sA0 + cb * 4096;
    const unsigned short* cB = sB0 + cb * 4096;
    bf16x8 af[4], bfr[4];
#pragma unroll
    for (int f = 0; f < 4; ++f) {
      int r = wr * 64 + f * 16 + l15;
      af[f] = *reinterpret_cast<const bf16x8*>(reinterpret_cast<const char*>(cA) + r * 64 + cq);
    }
#pragma unroll
    for (int f = 0; f < 4; ++f) {
      int r = wc * 64 + f * 16 + l15;
      bfr[f] = *reinterpret_cast<const bf16x8*>(reinterpret_cast<const char*>(cB) + r * 64 + cq);
    }

    if (t + 3 < 32) stage((t + 3) & 3, (t + 3) * 32);

    __builtin_amdgcn_s_setprio(1);
#pragma unroll
    for (int fm = 0; fm < 4; ++fm)
#pragma unroll
      for (int fn = 0; fn < 4; ++fn)
        acc[fm][fn] = __builtin_amdgcn_mfma_f32_16x16x32_bf16(af[fm], bfr[fn], acc[fm][fn], 0, 0, 0);
    __builtin_amdgcn_s_setprio(0);
  }
}

// ---------------- fused Q+K+V projection GEMM (M=12288 stacked bf16, K=1024) ----------------
// Operand-swapped: W = A (rows = d), X = B (rows = l) -> C rows = d -> vectorized 8B stores.
// Region by blockIdx.x: 0=Q (scaled 0.125*log2e), 1=K, 2=V (gated, per-head transposed).
__global__ __launch_bounds__(256) void k_gemm_qkv(const unsigned short* __restrict__ Xqkv,
                                                  const unsigned short* __restrict__ WhQ,
                                                  const unsigned short* __restrict__ WhK,
                                                  const unsigned short* __restrict__ WhV,
                                                  const float* __restrict__ bq,
                                                  const float* __restrict__ bk,
                                                  const float* __restrict__ bv,
                                                  const float* __restrict__ gate,
                                                  unsigned short* __restrict__ Qp,
                                                  unsigned short* __restrict__ Kp,
                                                  unsigned short* __restrict__ Vt) {
  __shared__ unsigned short sA[4][128 * 32];   // 32KB (W tiles)
  __shared__ unsigned short sB[4][128 * 32];   // 32KB (X tiles)
  const int tid = threadIdx.x;
  const int lane = tid & 63, wave = tid >> 6;
  const int l15 = lane & 15, l4 = lane >> 4;
  const int wr = wave >> 1, wc = wave & 1;
  const int m0 = blockIdx.x * 128, n0 = blockIdx.y * 128;
  const int region = m0 >> 12;                 // 0=Q, 1=K, 2=V
  const unsigned short* Wm = (region == 0) ? WhQ : (region == 1) ? WhK : WhV;
  const float* bias = (region == 0) ? bq : (region == 1) ? bk : bv;

  const f32x4 zero4 = {0.f, 0.f, 0.f, 0.f};
  f32x4 acc[4][4];
#pragma unroll
  for (int i = 0; i < 4; ++i)
#pragma unroll
    for (int j = 0; j < 4; ++j) acc[i][j] = zero4;

  // W as A-operand (rows = d dim), X as B-operand (rows = l dim)
  gemm_tile4(Wm, Xqkv, &sA[0][0], &sB[0][0], n0, m0, tid, acc);

  // acc[fw][fx]: C row n = n0 + wr*64 + fw*16 + l4*4 + j (d); C col m = m0 + wc*64 + fx*16 + l15 (l)
  if (region < 2) {
    unsigned short* Out = (region == 0) ? Qp : Kp;
    const float scale = (region == 0) ? 0.18033688011112042f : 1.0f;  // 0.125 * log2(e)
#pragma unroll
    for (int fw = 0; fw < 4; ++fw) {
      int nb = n0 + wr * 64 + fw * 16 + l4 * 4;
      int h = nb >> 6, d0 = nb & 63;
      float4 bv4 = *reinterpret_cast<const float4*>(bias + nb);
#pragma unroll
      for (int fx = 0; fx < 4; ++fx) {
        int rowm = (m0 + wc * 64 + fx * 16 + l15) & 4095;
        int b = rowm >> 11, l = rowm & 2047;
        float v0 = (acc[fw][fx][0] + bv4.x) * scale;
        float v1 = (acc[fw][fx][1] + bv4.y) * scale;
        float v2 = (acc[fw][fx][2] + bv4.z) * scale;
        float v3 = (acc[fw][fx][3] + bv4.w) * scale;
        uint2 wv;
        wv.x = cvtpk_bf16(v0, v1);
        wv.y = cvtpk_bf16(v2, v3);
        *reinterpret_cast<uint2*>(Out + (((size_t)(b * 16 + h) * 2048 + l) << 6) + d0) = wv;
      }
    }
  } else {
#pragma unroll
    for (int fw = 0; fw < 4; ++fw) {
      int nb = n0 + wr * 64 + fw * 16 + l4 * 4;
      int h = nb >> 6, d0 = nb & 63;
      float4 bv4 = *reinterpret_cast<const float4*>(bias + nb);
#pragma unroll
      for (int fx = 0; fx < 4; ++fx) {
        int rowm = (m0 + wc * 64 + fx * 16 + l15) & 4095;
        int b = rowm >> 11, l = rowm & 2047;
        float g = gate[rowm];
        float vj[4] = {(acc[fw][fx][0] + bv4.x) * g, (acc[fw][fx][1] + bv4.y) * g,
                       (acc[fw][fx][2] + bv4.z) * g, (acc[fw][fx][3] + bv4.w) * g};
#pragma unroll
        for (int j = 0; j < 4; ++j)
          Vt[((size_t)(b * 16 + h) * 64 + d0 + j) * 2048 + l] = f2bf(vj[j]);
      }
    }
  }
}

// ---------------- O projection GEMM, operand-swapped, float4 stores ----------------
__global__ __launch_bounds__(256) void k_gemm_f32(const unsigned short* __restrict__ A,
                                                  const unsigned short* __restrict__ Bt,
                                                  const float* __restrict__ bias,
                                                  float* __restrict__ C) {
  __shared__ unsigned short sA[4][128 * 32];
  __shared__ unsigned short sB[4][128 * 32];
  const int tid = threadIdx.x;
  const int lane = tid & 63, wave = tid >> 6;
  const int l15 = lane & 15, l4 = lane >> 4;
  const int wr = wave >> 1, wc = wave & 1;
  const int m0 = blockIdx.x * 128, n0 = blockIdx.y * 128;

  const f32x4 zero4 = {0.f, 0.f, 0.f, 0.f};
  f32x4 acc[4][4];
#pragma unroll
  for (int i = 0; i < 4; ++i)
#pragma unroll
    for (int j = 0; j < 4; ++j) acc[i][j] = zero4;

  // W as A-operand, activations as B-operand
  gemm_tile4(Bt, A, &sA[0][0], &sB[0][0], n0, m0, tid, acc);

#pragma unroll
  for (int fw = 0; fw < 4; ++fw) {
    int col0 = n0 + wr * 64 + fw * 16 + l4 * 4;
    float4 bv4 = *reinterpret_cast<const float4*>(bias + col0);
#pragma unroll
    for (int fx = 0; fx < 4; ++fx) {
      int row = m0 + wc * 64 + fx * 16 + l15;
      float4 o;
      o.x = acc[fw][fx][0] + bv4.x;
      o.y = acc[fw][fx][1] + bv4.y;
      o.z = acc[fw][fx][2] + bv4.z;
      o.w = acc[fw][fx][3] + bv4.w;
      *reinterpret_cast<float4*>(C + (size_t)row * 1024 + col0) = o;
    }
  }
}

// ---------------- flash attention: swapped-QK, pi-permuted K staging, lane-local P ----------------
// 3-buffer LDS + ONE barrier per tile; counted vmcnt(4) keeps next-tile loads in flight.
// Softmax denominator via ones-MFMA (same lane/reg layout as accO -> zero-shuffle epilogue).
__global__ __launch_bounds__(256) void k_flash(const unsigned short* __restrict__ Qp,
                                               const unsigned short* __restrict__ Kp,
                                               const unsigned short* __restrict__ Vt,
                                               unsigned short* __restrict__ O) {
  __shared__ unsigned short sK[3][64 * 64];   // 24KB
  __shared__ unsigned short sV[3][64 * 64];   // 24KB (V^T: rows=d, cols=keys)
  const int tid = threadIdx.x;
  const int lane = tid & 63, wave = tid >> 6;
  const int l15 = lane & 15, l4 = lane >> 4;
  const int bh = blockIdx.x;
  const int q0 = blockIdx.y * 128;
  const int b = bh >> 4, h = bh & 15;
  const size_t hBase = (size_t)bh * 2048 * 64;
  const int wofs = (tid & 192) * 16;          // wave-uniform LDS offset

  // Q fragments (B-operand): col=q (l15), k-elems kc*32 + l4*8..+7. Q pre-scaled by 0.125*log2e.
  bf16x8 qf[2][2];
#pragma unroll
  for (int fq = 0; fq < 2; ++fq) {
    int qrow = q0 + wave * 32 + fq * 16 + l15;
#pragma unroll
    for (int kc = 0; kc < 2; ++kc)
      qf[fq][kc] = *reinterpret_cast<const bf16x8*>(Qp + hBase + (size_t)qrow * 64 + kc * 32 + l4 * 8);
  }

  // all-ones bf16 B-fragment for the denominator MFMA
  const short one_bf = 0x3F80;
  const bf16x8 ones = {one_bf, one_bf, one_bf, one_bf, one_bf, one_bf, one_bf, one_bf};

  const f32x4 zero4 = {0.f, 0.f, 0.f, 0.f};
  f32x4 accO[2][4];
  f32x4 accL[2];                  // row-sum accumulator (denominator), same layout as accO
#pragma unroll
  for (int fq = 0; fq < 2; ++fq) {
    accL[fq] = zero4;
#pragma unroll
    for (int fd = 0; fd < 4; ++fd) accO[fq][fd] = zero4;
  }

  auto stage = [&](int buf, int kv0) {
#pragma unroll
    for (int i = 0; i < 2; ++i) {
      int id = i * 256 + tid;
      int r = id >> 3, c = id & 7;
      int sc = (c ^ (r & 7)) << 3;
      int kr = (r & 32) | ((r & 12) << 1) | ((r & 16) >> 2) | (r & 3);  // pi^-1(r)
      GLD16(Kp + hBase + (size_t)(kv0 + kr) * 64 + sc, (char*)sK[buf] + i * 4096 + wofs);
      GLD16(Vt + hBase + (size_t)r * 2048 + kv0 + sc, (char*)sV[buf] + i * 4096 + wofs);
    }
  };

  auto tile = [&](int t, int cb, int sb, bool last, bool dostage) {
    if (last) { asm volatile("s_waitcnt vmcnt(0)" ::: "memory"); }
    else      { asm volatile("s_waitcnt vmcnt(4)" ::: "memory"); }
    __builtin_amdgcn_sched_barrier(0);
    __builtin_amdgcn_s_barrier();
    __builtin_amdgcn_sched_barrier(0);

    // S^T = K Q^T: s[fk][fq], C row = permuted-k (l4*4+j), col = q (l15)
    f32x4 s[4][2];
#pragma unroll
    for (int fk = 0; fk < 4; ++fk)
#pragma unroll
      for (int fq = 0; fq < 2; ++fq) s[fk][fq] = zero4;
#pragma unroll
    for (int kc = 0; kc < 2; ++kc) {
      bf16x8 kf[4];
#pragma unroll
      for (int fk = 0; fk < 4; ++fk) {
        int r = fk * 16 + l15;
        kf[fk] = *reinterpret_cast<const bf16x8*>(
            reinterpret_cast<const char*>(sK[cb]) + r * 128 + (((kc * 4 + l4) ^ (r & 7)) * 16));
      }
      __builtin_amdgcn_s_setprio(1);
#pragma unroll
      for (int fk = 0; fk < 4; ++fk)
#pragma unroll
        for (int fq = 0; fq < 2; ++fq)
          s[fk][fq] = __builtin_amdgcn_mfma_f32_16x16x32_bf16(kf[fk], qf[fq][kc], s[fk][fq], 0, 0, 0);
      __builtin_amdgcn_s_setprio(0);
    }

    if (dostage) stage(sb, (t + 2) * 64);

    // p = 2^s; lane-local A-fragments (pi-staging made k contiguous in-lane)
    u32x4 pfa[2][2];
#pragma unroll
    for (int fq = 0; fq < 2; ++fq) {
      float p[4][4];
#pragma unroll
      for (int fk = 0; fk < 4; ++fk)
#pragma unroll
        for (int j = 0; j < 4; ++j) p[fk][j] = fast_exp2(s[fk][fq][j]);
      pfa[fq][0].x = cvtpk_bf16(p[0][0], p[0][1]);
      pfa[fq][0].y = cvtpk_bf16(p[0][2], p[0][3]);
      pfa[fq][0].z = cvtpk_bf16(p[1][0], p[1][1]);
      pfa[fq][0].w = cvtpk_bf16(p[1][2], p[1][3]);
      pfa[fq][1].x = cvtpk_bf16(p[2][0], p[2][1]);
      pfa[fq][1].y = cvtpk_bf16(p[2][2], p[2][3]);
      pfa[fq][1].z = cvtpk_bf16(p[3][0], p[3][1]);
      pfa[fq][1].w = cvtpk_bf16(p[3][2], p[3][3]);
    }

    // O += P * V  (A = lane-local P, B = V^T rows d); denominator via ones-MFMA
#pragma unroll
    for (int kc = 0; kc < 2; ++kc) {
      bf16x8 vf[4];
#pragma unroll
      for (int fd = 0; fd < 4; ++fd) {
        int r = fd * 16 + l15;
        vf[fd] = *reinterpret_cast<const bf16x8*>(
            reinterpret_cast<const char*>(sV[cb]) + r * 128 + (((kc * 4 + l4) ^ (r & 7)) * 16));
      }
      __builtin_amdgcn_s_setprio(1);
#pragma unroll
      for (int fq = 0; fq < 2; ++fq) {
        bf16x8 pf = __builtin_bit_cast(bf16x8, pfa[fq][kc]);
#pragma unroll
        for (int fd = 0; fd < 4; ++fd)
          accO[fq][fd] = __builtin_amdgcn_mfma_f32_16x16x32_bf16(pf, vf[fd], accO[fq][fd], 0, 0, 0);
        accL[fq] = __builtin_amdgcn_mfma_f32_16x16x32_bf16(pf, ones, accL[fq], 0, 0, 0);
      }
      __builtin_amdgcn_s_setprio(0);
    }
  };

  stage(0, 0);
  stage(1, 64);

  for (int base = 0; base < 30; base += 3) {
    tile(base + 0, 0, 2, false, true);
    tile(base + 1, 1, 0, false, true);
    tile(base + 2, 2, 1, false, true);
  }
  tile(30, 0, 2, false, false);
  tile(31, 1, 0, true, false);

  // epilogue: denominator already in matching lane/reg layout -> divide and store bf16
#pragma unroll
  for (int fq = 0; fq < 2; ++fq)
#pragma unroll
    for (int j = 0; j < 4; ++j) {
      float li = 1.0f / accL[fq][j];
      int qw = q0 + wave * 32 + fq * 16 + l4 * 4 + j;
#pragma unroll
      for (int fd = 0; fd < 4; ++fd) {
        int col = h * 64 + fd * 16 + l15;
        O[(size_t)(b * 2048 + qw) * 1024 + col] = f2bf(accO[fq][fd][j] * li);
      }
    }
}

extern "C" void kernel_launch(void* const* d_in, const int* in_sizes, int n_in,
                              void* d_out, int out_size, void* d_ws, size_t ws_size,
                              hipStream_t stream) {
  const float* q_x = (const float*)d_in[0];
  const float* k_x = (const float*)d_in[1];
  const float* v_x = (const float*)d_in[2];
  const float* E   = (const float*)d_in[3];
  const float* Wq  = (const float*)d_in[4];
  const float* bq  = (const float*)d_in[5];
  const float* Wk  = (const float*)d_in[6];
  const float* bk  = (const float*)d_in[7];
  const float* Wv  = (const float*)d_in[8];
  const float* bv  = (const float*)d_in[9];
  const float* Wo  = (const float*)d_in[10];
  const float* bo  = (const float*)d_in[11];
  float* out = (float*)d_out;

  char* w = (char*)d_ws;
  unsigned short* Wt4  = (unsigned short*)(w + 0);          // 4x 1024x1024 bf16 = 8 MB (Q,K,V,O)
  unsigned short* Whq  = Wt4;
  unsigned short* Whk  = Wt4 + 1048576;
  unsigned short* Wtv  = Wt4 + 2097152;
  unsigned short* Wto  = Wt4 + 3145728;
  unsigned short* Xqkv = (unsigned short*)(w + 8388608);    // 12288x1024 bf16 = 24 MB
  unsigned short* Qp   = (unsigned short*)(w + 33554432);   // 8 MB
  unsigned short* Kpp  = (unsigned short*)(w + 41943040);   // 8 MB
  unsigned short* Vtp  = (unsigned short*)(w + 50331648);   // 8 MB
  unsigned short* Obf  = (unsigned short*)(w + 58720256);   // 8 MB
  float*          gate = (float*)(w + 67108864);            // 16 KB

  k_gate<<<16, 256, 0, stream>>>(E, gate);

  // all 4 weight transposes in one dispatch
  k_pack_wT4<<<dim3(32, 32, 4), 256, 0, stream>>>(Wq, Wk, Wv, Wo, Wt4);

  // Q, K, V inputs packed plain bf16, stacked along M (12288 rows), one dispatch
  k_pack_plain3<<<dim3(2048, 3), 256, 0, stream>>>(q_x, k_x, v_x, Xqkv);

  // fused Q+K+V projections: per-head bf16 epilogues (Q scaled; V gated+transposed)
  k_gemm_qkv<<<dim3(96, 8), 256, 0, stream>>>(Xqkv, Whq, Whk, Wtv, bq, bk, bv, gate,
                                              Qp, Kpp, Vtp);

  // attention -> bf16 (b,l,1024)
  k_flash<<<dim3(32, 16), 256, 0, stream>>>(Qp, Kpp, Vtp, Obf);

  // output projection
  k_gemm_f32<<<dim3(32, 8), 256, 0, stream>>>(Obf, Wto, bo, out);
}